// Round 3
// baseline (16396.425 us; speedup 1.0000x reference)
//
#include <hip/hip_runtime.h>
#include <hip/hip_bf16.h>

// ============================================================================
// GRU seq2seq (3-layer enc + 3-cell dec + linear), B=2048, H=60, F=1, fp32.
//
// Round 3:
//  - 512 blocks x 4 batch-rows (was 128 x 16), __launch_bounds__(768, 6):
//    2 independent barrier-domains (blocks) per CU -> mutual stall-filling.
//    MFMA rows 4-15 are padding (init 0, bounded dynamics, never stored).
//  - Split MFMA accumulator chains 6 -> 3+3 (halve dependent latency).
//  - Both A-fragment LDS loads issued before any MFMA.
//  - (kept) hi/lo bf16 ring planes, VGPR/AGPR-resident weights, x prefetch.
// ============================================================================

typedef float  f32x4  __attribute__((ext_vector_type(4)));
typedef short  bf16x8 __attribute__((ext_vector_type(8)));

#define ROWS 4            // batch rows per block
#define NBLK (2048 / ROWS)

struct CellB  { const float* bih; const float* bhh; const float* wih_vec; };
struct PhaseArgs {
  const float* xseq;          // [2048][512] fp32 (inputs or outputs)
  const unsigned short* frags;
  CellB cell[3];
  const float* hfin_rd;       // dec: [3][2048][64] fp32 (enc final h)
  float* hfin_wr;             // enc
  const float* lin_w;         // [60]
  const float* lin_b;         // [1]
  float* y;                   // [2048][512]
};
struct PrepArgs {
  const float* w[12];         // cell-major: (wih, whh) x 6 cells
  int din[12];
  unsigned short* out;
};

__device__ __forceinline__ unsigned int rne16(float x) {
  unsigned int u = __float_as_uint(x);
  return (u + 0x7fffu + ((u >> 16) & 1u)) >> 16;   // round-to-nearest-even bf16
}
__device__ __forceinline__ float bf2f(unsigned int b) {
  return __uint_as_float(b << 16);
}
union BU { __hip_bfloat16 b; unsigned short u; };
__device__ __forceinline__ unsigned short f2bf(float x) {
  BU c; c.b = __float2bfloat16(x); return c.u;
}
__device__ __forceinline__ float bfu2f(unsigned short s) {
  BU c; c.u = s; return __bfloat162float(c.b);
}

// ---------------------------------------------------------------------------
// Prep: build B-fragments (bf16 hi/lo) for all 6 cells x {wih, whh}.
// frag layout: frag_idx = ((cell*2+mat)*12 + tile)*4 + s2*2 + sp
//              short off = frag_idx*512 + lane*8 + e
// ---------------------------------------------------------------------------
__global__ void prep_frags(PrepArgs P) {
  int id = blockIdx.x * 256 + threadIdx.x;       // 1152*256 = 294912 total
  int e    = id & 7;
  int lane = (id >> 3) & 63;
  int sp   = (id >> 9) & 1;
  int s2   = (id >> 10) & 1;
  int rest = id >> 11;
  int tile = rest % 12;
  int cm   = rest / 12;
  if (cm >= 12) return;
  const float* W = P.w[cm];
  int din = P.din[cm];
  int c = tile * 16 + (lane & 15);
  int j = c & 63, sec = c >> 6;                  // sec: 0=r,1=z,2=n
  int k = s2 * 32 + (lane >> 4) * 8 + e;
  float v = 0.f;
  if (j < 60 && k < din) v = W[(sec * 60 + j) * din + k];
  unsigned int hi = rne16(v);
  unsigned short o = (unsigned short)(sp ? rne16(v - bf2f(hi)) : hi);
  P.out[id] = o;
}

// ---------------------------------------------------------------------------
// A-fragment loads from hi/lo bf16 planes (row stride 72 shorts = 144 B).
// ---------------------------------------------------------------------------
__device__ __forceinline__ void load_A(const unsigned short* baseH,
                                       const unsigned short* baseL,
                                       int c16, int q16,
                                       bf16x8 Ahi[2], bf16x8 Alo[2]) {
  const unsigned short* pH = baseH + c16 * 72 + q16 * 8;
  const unsigned short* pL = baseL + c16 * 72 + q16 * 8;
  Ahi[0] = *(const bf16x8*)(pH);
  Ahi[1] = *(const bf16x8*)(pH + 32);
  Alo[0] = *(const bf16x8*)(pL);
  Alo[1] = *(const bf16x8*)(pL + 32);
}

// 3-product (hi*Whi + lo*Whi + hi*Wlo), two independent 3-deep chains
__device__ __forceinline__ f32x4 mm3(f32x4 acc, const bf16x8 Ahi[2],
                                     const bf16x8 Alo[2], const bf16x8 B[2][2]) {
  f32x4 a2 = {0.f, 0.f, 0.f, 0.f};
  acc = __builtin_amdgcn_mfma_f32_16x16x32_bf16(Ahi[0], B[0][0], acc, 0, 0, 0);
  a2  = __builtin_amdgcn_mfma_f32_16x16x32_bf16(Alo[0], B[0][0], a2,  0, 0, 0);
  acc = __builtin_amdgcn_mfma_f32_16x16x32_bf16(Ahi[1], B[1][0], acc, 0, 0, 0);
  a2  = __builtin_amdgcn_mfma_f32_16x16x32_bf16(Alo[1], B[1][0], a2,  0, 0, 0);
  acc = __builtin_amdgcn_mfma_f32_16x16x32_bf16(Ahi[0], B[0][1], acc, 0, 0, 0);
  a2  = __builtin_amdgcn_mfma_f32_16x16x32_bf16(Ahi[1], B[1][1], a2,  0, 0, 0);
  return acc + a2;
}

// 2-product (hi*Whi + lo*Whi), two independent 2-deep chains
__device__ __forceinline__ f32x4 mm2(f32x4 acc, const bf16x8 Ahi[2],
                                     const bf16x8 Alo[2], const bf16x8 B[2]) {
  f32x4 a2 = {0.f, 0.f, 0.f, 0.f};
  acc = __builtin_amdgcn_mfma_f32_16x16x32_bf16(Ahi[0], B[0], acc, 0, 0, 0);
  a2  = __builtin_amdgcn_mfma_f32_16x16x32_bf16(Alo[0], B[0], a2,  0, 0, 0);
  acc = __builtin_amdgcn_mfma_f32_16x16x32_bf16(Ahi[1], B[1], acc, 0, 0, 0);
  a2  = __builtin_amdgcn_mfma_f32_16x16x32_bf16(Alo[1], B[1], a2,  0, 0, 0);
  return acc + a2;
}

// ---------------------------------------------------------------------------
// Fused 3-stage GRU pipeline. IS_DEC=0: encoder; IS_DEC=1: decoder (+linear).
// ---------------------------------------------------------------------------
template <int IS_DEC>
__global__ __launch_bounds__(768, 6) void gru_phase(PhaseArgs P) {
  __shared__ alignas(16) unsigned short ringH[3 * 2 * 16 * 72];
  __shared__ alignas(16) unsigned short ringL[3 * 2 * 16 * 72];
  __shared__ float y_part[2][4][16];

  const int tid  = threadIdx.x;
  const int lane = tid & 63;
  const int wid  = tid >> 6;
  const int g    = wid >> 2;      // layer/cell index 0..2
  const int w    = wid & 3;       // tile-triple index 0..3
  const int c16  = lane & 15;
  const int q16  = lane >> 4;
  const int row_base = blockIdx.x * ROWS;
  const int c    = w * 16 + c16;  // logical h-column 0..63
  const bool cv  = (c < 60);
  const int cell = (IS_DEC ? 3 : 0) + g;
  const bool din1 = (g == 0);
  const bool rv   = (q16 == 0);   // rows 4q16+q valid only for q16==0 (ROWS=4)

  // per-lane constants
  const float* bih = P.cell[g].bih;
  const float* bhh = P.cell[g].bhh;
  float b_r  = cv ? bih[c] + bhh[c]           : 0.f;
  float b_z  = cv ? bih[60 + c] + bhh[60 + c] : 0.f;
  float b_hn = cv ? bhh[120 + c]              : 0.f;
  float b_in = cv ? bih[120 + c]              : 0.f;
  float w_r = 0.f, w_z = 0.f, w_n = 0.f;
  if (din1 && cv) {
    const float* wv = P.cell[g].wih_vec;
    w_r = wv[c]; w_z = wv[60 + c]; w_n = wv[120 + c];
  }
  float lw = 0.f, lb = 0.f;
  if (IS_DEC && g == 2) { lw = cv ? P.lin_w[c] : 0.f; lb = P.lin_b[0]; }

  // persistent weight fragments
  bf16x8 Bh[3][2][2], Bx[3][2];
#pragma unroll
  for (int T = 0; T < 3; ++T)
#pragma unroll
    for (int s2 = 0; s2 < 2; ++s2) {
      const int tile = w + 4 * T;
#pragma unroll
      for (int sp = 0; sp < 2; ++sp)
        Bh[T][s2][sp] = *(const bf16x8*)(P.frags +
            (size_t)(((cell * 2 + 1) * 12 + tile) * 4 + s2 * 2 + sp) * 512 + lane * 8);
      Bx[T][s2] = *(const bf16x8*)(P.frags +
          (size_t)(((cell * 2 + 0) * 12 + tile) * 4 + s2 * 2 + 0) * 512 + lane * 8);
    }

  // h0 (enc: zeros; dec: encoder final h for valid rows) + ring init
  float hreg[4];
#pragma unroll
  for (int q = 0; q < 4; ++q) {
    float h0 = 0.f;
    if (IS_DEC && rv)
      h0 = P.hfin_rd[((size_t)(2 - g) * 2048 + row_base + q) * 64 + c];
    hreg[q] = h0;
    unsigned short hb = f2bf(h0);
    unsigned short lo = f2bf(h0 - bfu2f(hb));
    int ro = ((g * 2 + 1) * 16 + 4 * q16 + q) * 72 + c;
    ringH[ro] = hb; ringL[ro] = lo;
  }

  // x prefetch (t=0) for din=1 waves (valid rows only; padding rows x=0)
  float xcur[4] = {0.f, 0.f, 0.f, 0.f};
  if (din1 && rv) {
    const float* xp = P.xseq + (size_t)row_base * 512;
#pragma unroll
    for (int q = 0; q < 4; ++q) xcur[q] = xp[(size_t)q * 512];
  }
  __syncthreads();

  const int NS = IS_DEC ? 515 : 514;
#pragma unroll 1
  for (int s = 0; s < NS; ++s) {
    // decoder: finalize y for t = s-3 (partials written last slot)
    if (IS_DEC && g == 2 && w == 0 && lane < ROWS) {
      int ty = s - 3;
      if (ty >= 0) {
        float yv = y_part[ty & 1][0][lane] + y_part[ty & 1][1][lane] +
                   y_part[ty & 1][2][lane] + y_part[ty & 1][3][lane] + lb;
        P.y[(size_t)(row_base + lane) * 512 + ty] = yv;
      }
    }

    const int t = s - g;
    if (t >= 0 && t < 512) {
      // ---- issue both A-fragment loads up front
      const int rdo = (g * 2 + ((t + 1) & 1)) * 16 * 72;
      bf16x8 Ahi[2], Alo[2];
      load_A(ringH + rdo, ringL + rdo, c16, q16, Ahi, Alo);
      bf16x8 Xhi[2], Xlo[2];
      if (!din1) {
        const int rxo = ((g - 1) * 2 + (t & 1)) * 16 * 72;
        load_A(ringH + rxo, ringL + rxo, c16, q16, Xhi, Xlo);
      }

      f32x4 aR  = {b_r, b_r, b_r, b_r};
      f32x4 aZ  = {b_z, b_z, b_z, b_z};
      f32x4 aHN = {b_hn, b_hn, b_hn, b_hn};
      f32x4 aIN = {b_in, b_in, b_in, b_in};
      aR  = mm3(aR,  Ahi, Alo, Bh[0]);
      aZ  = mm3(aZ,  Ahi, Alo, Bh[1]);
      aHN = mm3(aHN, Ahi, Alo, Bh[2]);

      if (din1) {
#pragma unroll
        for (int q = 0; q < 4; ++q) {
          aR[q]  += xcur[q] * w_r;
          aZ[q]  += xcur[q] * w_z;
          aIN[q] += xcur[q] * w_n;
        }
        if (rv && t + 1 < 512) {                // prefetch next step's x
          const float* xp = P.xseq + (size_t)row_base * 512 + (t + 1);
#pragma unroll
          for (int q = 0; q < 4; ++q) xcur[q] = xp[(size_t)q * 512];
        }
      } else {
        aR  = mm2(aR,  Xhi, Xlo, Bx[0]);
        aZ  = mm2(aZ,  Xhi, Xlo, Bx[1]);
        aIN = mm2(aIN, Xhi, Xlo, Bx[2]);
      }

      // ---- activations + state update (full fp32)
#pragma unroll
      for (int q = 0; q < 4; ++q) {
        float r = __builtin_amdgcn_rcpf(1.f + __expf(-aR[q]));
        float z = __builtin_amdgcn_rcpf(1.f + __expf(-aZ[q]));
        float na = aIN[q] + r * aHN[q];
        na = fminf(fmaxf(na, -15.f), 15.f);
        float e2 = __expf(2.f * na);
        float n = (e2 - 1.f) * __builtin_amdgcn_rcpf(e2 + 1.f);
        hreg[q] = n + z * (hreg[q] - n);
      }

      // ---- publish h_t (hi/lo planes) to ring[parity t&1]
      {
        unsigned short* wH = ringH + (g * 2 + (t & 1)) * 16 * 72;
        unsigned short* wL = ringL + (g * 2 + (t & 1)) * 16 * 72;
#pragma unroll
        for (int q = 0; q < 4; ++q) {
          float h = hreg[q];
          unsigned short hb = f2bf(h);
          unsigned short lo = f2bf(h - bfu2f(hb));
          int ro = (4 * q16 + q) * 72 + c;
          wH[ro] = hb; wL[ro] = lo;
        }
      }

      // ---- encoder: store final hidden state (valid rows only)
      if (!IS_DEC && t == 511 && rv) {
#pragma unroll
        for (int q = 0; q < 4; ++q)
          P.hfin_wr[((size_t)g * 2048 + row_base + q) * 64 + c] = hreg[q];
      }

      // ---- decoder: y partials (reduce over this wave's 16 columns)
      if (IS_DEC && g == 2) {
        float part[4];
#pragma unroll
        for (int q = 0; q < 4; ++q) part[q] = hreg[q] * lw;
#pragma unroll
        for (int m = 1; m < 16; m <<= 1) {
#pragma unroll
          for (int q = 0; q < 4; ++q) part[q] += __shfl_xor(part[q], m, 64);
        }
        if (c16 == 0) {
#pragma unroll
          for (int q = 0; q < 4; ++q) y_part[t & 1][w][4 * q16 + q] = part[q];
        }
      }
    }
    __syncthreads();
  }
}

// ---------------------------------------------------------------------------
extern "C" void kernel_launch(void* const* d_in, const int* in_sizes, int n_in,
                              void* d_out, int out_size, void* d_ws, size_t ws_size,
                              hipStream_t stream) {
  (void)in_sizes; (void)n_in; (void)out_size; (void)ws_size;
  const float* inputs  = (const float*)d_in[0];
  const float* outputs = (const float*)d_in[1];

  unsigned short* frags = (unsigned short*)d_ws;                 // 589824 B
  float* hfin = (float*)((char*)d_ws + (size_t)6 * 2 * 12 * 4 * 512 * 2); // 1.5 MB

  static const int ofs[6]  = {2, 6, 10, 14, 18, 22};  // enc0,enc1,enc2,c1,c2,c3
  static const int dins[6] = {1, 60, 60, 1, 60, 60};

  PrepArgs pa;
  for (int ci = 0; ci < 6; ++ci) {
    pa.w[ci * 2 + 0]   = (const float*)d_in[ofs[ci] + 0];  // wih
    pa.w[ci * 2 + 1]   = (const float*)d_in[ofs[ci] + 1];  // whh
    pa.din[ci * 2 + 0] = dins[ci];
    pa.din[ci * 2 + 1] = 60;
  }
  pa.out = frags;
  prep_frags<<<dim3(1152), dim3(256), 0, stream>>>(pa);

  PhaseArgs ea;
  ea.xseq = inputs; ea.frags = frags;
  for (int gg = 0; gg < 3; ++gg) {
    ea.cell[gg].bih     = (const float*)d_in[ofs[gg] + 2];
    ea.cell[gg].bhh     = (const float*)d_in[ofs[gg] + 3];
    ea.cell[gg].wih_vec = (const float*)d_in[ofs[gg] + 0];
  }
  ea.hfin_rd = hfin; ea.hfin_wr = hfin;
  ea.lin_w = (const float*)d_in[26]; ea.lin_b = (const float*)d_in[27];
  ea.y = (float*)d_out;
  gru_phase<0><<<dim3(NBLK), dim3(768), 0, stream>>>(ea);

  PhaseArgs da = ea;
  da.xseq = outputs;
  for (int gg = 0; gg < 3; ++gg) {
    da.cell[gg].bih     = (const float*)d_in[ofs[3 + gg] + 2];
    da.cell[gg].bhh     = (const float*)d_in[ofs[3 + gg] + 3];
    da.cell[gg].wih_vec = (const float*)d_in[ofs[3 + gg] + 0];
  }
  gru_phase<1><<<dim3(NBLK), dim3(768), 0, stream>>>(da);
}

// Round 4
// 2664.737 us; speedup vs baseline: 6.1531x; 6.1531x over previous
//
#include <hip/hip_runtime.h>
#include <hip/hip_bf16.h>

// ============================================================================
// GRU seq2seq (3-layer enc + 3-cell dec + linear), B=2048, H=60, F=1, fp32.
//
// Round 4 (vs round 2 = 865us/phase):
//  - 6 waves/block (384 thr): 2 waves per group, each owning 2 h-col tiles
//    (6 gate tiles). LDS b128 reads/step: 80 -> 44 (A reused across tiles).
//  - Ring = ONE packed u32 plane per (group,parity): element = hi | lo<<16.
//    Writes 96xb16 -> 48xb32; read unpack = 1 v_perm_b32 per output reg.
//  - Decoder y via MFMA on g0w0 (A = g2's ring, B = lin_w hi/lo fragments):
//    removes 64 DS-shuffle ops/step from the shared LDS pipe.
//  - Raw lgkmcnt(0)+s_barrier per step (no vmcnt drain of prefetch/stores).
//  - __launch_bounds__(384, 2): 256-reg budget, ~236 worst-path estimate.
//  - Numerics identical to round 2 (bf16 hi/lo h, mm3 h-path, mm2 x-path).
// ============================================================================

typedef float  f32x4  __attribute__((ext_vector_type(4)));
typedef short  bf16x8 __attribute__((ext_vector_type(8)));

struct CellB  { const float* bih; const float* bhh; const float* wih_vec; };
struct PhaseArgs {
  const float* xseq;          // [2048][512] fp32
  const unsigned short* frags;
  CellB cell[3];
  const float* hfin_rd;       // dec: [3][2048][64] fp32
  float* hfin_wr;             // enc
  const float* lin_b;         // [1]
  float* y;                   // [2048][512]
};
struct PrepArgs {
  const float* w[13];         // (wih,whh) x 6 cells, then lin_w
  int din[13];
  unsigned short* out;
};

__device__ __forceinline__ unsigned int rne16(float x) {
  unsigned int u = __float_as_uint(x);
  return (u + 0x7fffu + ((u >> 16) & 1u)) >> 16;
}
__device__ __forceinline__ float bf2f(unsigned int b) {
  return __uint_as_float(b << 16);
}
union BU { __hip_bfloat16 b; unsigned short u; };
__device__ __forceinline__ unsigned short f2bf(float x) {
  BU c; c.b = __float2bfloat16(x); return c.u;
}
__device__ __forceinline__ float bfu2f(unsigned short s) {
  BU c; c.u = s; return __bfloat162float(c.b);
}
__device__ __forceinline__ unsigned int pack_hl(float h) {
  unsigned short hb = f2bf(h);
  float rf = h - bfu2f(hb);
  unsigned short lo = f2bf(rf);
  return (unsigned int)hb | ((unsigned int)lo << 16);
}
__device__ __forceinline__ void wg_barrier() {
  asm volatile("s_waitcnt lgkmcnt(0)" ::: "memory");
  __builtin_amdgcn_s_barrier();
}

// ---------------------------------------------------------------------------
// Prep: B-fragments (bf16 hi/lo). frag_idx = (cm*12 + tile)*4 + s2*2 + sp,
// cm = cell*2+mat for 6 cells x {wih,whh}; cm=12 = lin_w (tile 0 only).
// B element (lane,e): col c = tile*16+(lane&15), k = s2*32+(lane>>4)*8+e.
// ---------------------------------------------------------------------------
__global__ void prep_frags(PrepArgs P) {
  int id = blockIdx.x * 256 + threadIdx.x;       // 1160*256 = 296960
  int e    = id & 7;
  int lane = (id >> 3) & 63;
  int sp   = (id >> 9) & 1;
  int s2   = (id >> 10) & 1;
  int rest = id >> 11;
  int tile = rest % 12;
  int cm   = rest / 12;
  if (cm > 12) return;
  const float* W = P.w[cm];
  int din = P.din[cm];
  int c = tile * 16 + (lane & 15);
  int k = s2 * 32 + (lane >> 4) * 8 + e;
  float v = 0.f;
  if (cm == 12) {
    if (c == 0 && k < 60) v = W[k];              // lin_w column
  } else {
    int j = c & 63, sec = c >> 6;
    if (j < 60 && k < din) v = W[(sec * 60 + j) * din + k];
  }
  unsigned int hi = rne16(v);
  unsigned short o = (unsigned short)(sp ? rne16(v - bf2f(hi)) : hi);
  P.out[id] = o;
}

// ---------------------------------------------------------------------------
// A-fragment load+unpack from packed u32 ring (row stride 68 dwords).
// A[r][k]: r = lane&15, k = s2*32 + (lane>>4)*8 + e.
// ---------------------------------------------------------------------------
__device__ __forceinline__ void load_Apk(const unsigned int* rb, int c16, int q16,
                                         bf16x8 Ahi[2], bf16x8 Alo[2]) {
#pragma unroll
  for (int s2 = 0; s2 < 2; ++s2) {
    const uint4 a = *(const uint4*)(rb + c16 * 68 + s2 * 32 + q16 * 8);
    const uint4 b = *(const uint4*)(rb + c16 * 68 + s2 * 32 + q16 * 8 + 4);
    union { unsigned int u[4]; bf16x8 v; } hh, ll;
    hh.u[0] = __builtin_amdgcn_perm(a.y, a.x, 0x05040100u);
    hh.u[1] = __builtin_amdgcn_perm(a.w, a.z, 0x05040100u);
    hh.u[2] = __builtin_amdgcn_perm(b.y, b.x, 0x05040100u);
    hh.u[3] = __builtin_amdgcn_perm(b.w, b.z, 0x05040100u);
    ll.u[0] = __builtin_amdgcn_perm(a.y, a.x, 0x07060302u);
    ll.u[1] = __builtin_amdgcn_perm(a.w, a.z, 0x07060302u);
    ll.u[2] = __builtin_amdgcn_perm(b.y, b.x, 0x07060302u);
    ll.u[3] = __builtin_amdgcn_perm(b.w, b.z, 0x07060302u);
    Ahi[s2] = hh.v; Alo[s2] = ll.v;
  }
}

// 3-product (hi*Whi + lo*Whi + hi*Wlo), two independent 3-deep chains
__device__ __forceinline__ f32x4 mm3(f32x4 acc, const bf16x8 Ahi[2],
                                     const bf16x8 Alo[2], const bf16x8 B[2][2]) {
  f32x4 a2 = {0.f, 0.f, 0.f, 0.f};
  acc = __builtin_amdgcn_mfma_f32_16x16x32_bf16(Ahi[0], B[0][0], acc, 0, 0, 0);
  a2  = __builtin_amdgcn_mfma_f32_16x16x32_bf16(Alo[0], B[0][0], a2,  0, 0, 0);
  acc = __builtin_amdgcn_mfma_f32_16x16x32_bf16(Ahi[1], B[1][0], acc, 0, 0, 0);
  a2  = __builtin_amdgcn_mfma_f32_16x16x32_bf16(Alo[1], B[1][0], a2,  0, 0, 0);
  acc = __builtin_amdgcn_mfma_f32_16x16x32_bf16(Ahi[0], B[0][1], acc, 0, 0, 0);
  a2  = __builtin_amdgcn_mfma_f32_16x16x32_bf16(Ahi[1], B[1][1], a2,  0, 0, 0);
  return acc + a2;
}
// 2-product (hi*Whi + lo*Whi)
__device__ __forceinline__ f32x4 mm2(f32x4 acc, const bf16x8 Ahi[2],
                                     const bf16x8 Alo[2], const bf16x8 B[2]) {
  f32x4 a2 = {0.f, 0.f, 0.f, 0.f};
  acc = __builtin_amdgcn_mfma_f32_16x16x32_bf16(Ahi[0], B[0], acc, 0, 0, 0);
  a2  = __builtin_amdgcn_mfma_f32_16x16x32_bf16(Alo[0], B[0], a2,  0, 0, 0);
  acc = __builtin_amdgcn_mfma_f32_16x16x32_bf16(Ahi[1], B[1], acc, 0, 0, 0);
  a2  = __builtin_amdgcn_mfma_f32_16x16x32_bf16(Alo[1], B[1], a2,  0, 0, 0);
  return acc + a2;
}

// ---------------------------------------------------------------------------
template <int IS_DEC>
__global__ __launch_bounds__(384, 2) void gru_phase(PhaseArgs P) {
  __shared__ alignas(16) unsigned int ring[3 * 2 * 16 * 68];  // packed hi|lo

  const int tid  = threadIdx.x;
  const int lane = tid & 63;
  const int wid  = tid >> 6;
  const int g    = wid >> 1;      // group 0..2
  const int w    = wid & 1;       // wave-in-group 0..1
  const int c16  = lane & 15;
  const int q16  = lane >> 4;
  const int row_base = blockIdx.x * 16;
  const int cell = (IS_DEC ? 3 : 0) + g;
  const bool din1 = (g == 0);
  const bool yduty = (IS_DEC && din1 && w == 0);

  int  cH[2];
#pragma unroll
  for (int ht = 0; ht < 2; ++ht) cH[ht] = (2 * w + ht) * 16 + c16;

  // per-lane constants
  const float* bih = P.cell[g].bih;
  const float* bhh = P.cell[g].bhh;
  float b_r[2], b_z[2], b_hn[2], b_in[2], w_r[2], w_z[2], w_n[2];
#pragma unroll
  for (int ht = 0; ht < 2; ++ht) {
    const int c = cH[ht];
    const bool cv = (c < 60);
    b_r[ht]  = cv ? bih[c] + bhh[c]           : 0.f;
    b_z[ht]  = cv ? bih[60 + c] + bhh[60 + c] : 0.f;
    b_hn[ht] = cv ? bhh[120 + c]              : 0.f;
    b_in[ht] = cv ? bih[120 + c]              : 0.f;
    w_r[ht] = w_z[ht] = w_n[ht] = 0.f;
    if (din1 && cv) {
      const float* wv = P.cell[g].wih_vec;
      w_r[ht] = wv[c]; w_z[ht] = wv[60 + c]; w_n[ht] = wv[120 + c];
    }
  }
  float lb = 0.f;
  if (yduty) lb = P.lin_b[0];

  // weight fragments (Bh: 2ht x 3gate x 2s2 x {Whi,Wlo}; Bx: hi only)
  bf16x8 Bh[2][3][2][2], Bx[2][3][2], Lw[2][2];
#pragma unroll
  for (int ht = 0; ht < 2; ++ht)
#pragma unroll
    for (int gt = 0; gt < 3; ++gt)
#pragma unroll
      for (int s2 = 0; s2 < 2; ++s2) {
        const int tile = (2 * w + ht) + 4 * gt;
#pragma unroll
        for (int sp = 0; sp < 2; ++sp)
          Bh[ht][gt][s2][sp] = *(const bf16x8*)(P.frags +
              (size_t)(((cell * 2 + 1) * 12 + tile) * 4 + s2 * 2 + sp) * 512 + lane * 8);
      }
  if (!din1) {
#pragma unroll
    for (int ht = 0; ht < 2; ++ht)
#pragma unroll
      for (int gt = 0; gt < 3; ++gt)
#pragma unroll
        for (int s2 = 0; s2 < 2; ++s2) {
          const int tile = (2 * w + ht) + 4 * gt;
          Bx[ht][gt][s2] = *(const bf16x8*)(P.frags +
              (size_t)(((cell * 2 + 0) * 12 + tile) * 4 + s2 * 2 + 0) * 512 + lane * 8);
        }
  }
  if (yduty) {
#pragma unroll
    for (int s2 = 0; s2 < 2; ++s2)
#pragma unroll
      for (int sp = 0; sp < 2; ++sp)
        Lw[s2][sp] = *(const bf16x8*)(P.frags +
            (size_t)((144) * 4 + s2 * 2 + sp) * 512 + lane * 8);
  }

  // h0 + ring init (parity 1 = read slot of t=0)
  float hreg[2][4];
#pragma unroll
  for (int ht = 0; ht < 2; ++ht)
#pragma unroll
    for (int q = 0; q < 4; ++q) {
      float h0 = 0.f;
      if (IS_DEC)
        h0 = P.hfin_rd[((size_t)(2 - g) * 2048 + row_base + 4 * q16 + q) * 64 + cH[ht]];
      hreg[ht][q] = h0;
      ring[((g * 2 + 1) * 16 + 4 * q16 + q) * 68 + cH[ht]] = pack_hl(h0);
    }

  // x prefetch (t=0) for g0
  float xcur[4] = {0.f, 0.f, 0.f, 0.f};
  if (din1) {
    const float* xp = P.xseq + (size_t)row_base * 512;
#pragma unroll
    for (int q = 0; q < 4; ++q) xcur[q] = xp[(size_t)(4 * q16 + q) * 512];
  }
  wg_barrier();

  const int NS = IS_DEC ? 515 : 514;
#pragma unroll 1
  for (int s = 0; s < NS; ++s) {
    // decoder: y_{s-3} via MFMA on g0w0 (A = g2 ring written last slot)
    if (yduty && s >= 3) {
      const int ty = s - 3;
      const unsigned int* rb = ring + (2 * 2 + ((s + 1) & 1)) * 16 * 68;
      bf16x8 Yhi[2], Ylo[2];
      load_Apk(rb, c16, q16, Yhi, Ylo);
      f32x4 ya = {lb, lb, lb, lb};
      ya = mm3(ya, Yhi, Ylo, Lw);
      if (c16 == 0) {
#pragma unroll
        for (int q = 0; q < 4; ++q)
          P.y[(size_t)(row_base + 4 * q16 + q) * 512 + ty] = ya[q];
      }
    }

    const int t = s - g;
    if (t >= 0 && t < 512) {
      const unsigned int* rb = ring + (g * 2 + ((t + 1) & 1)) * 16 * 68;
      bf16x8 Ahi[2], Alo[2];
      load_Apk(rb, c16, q16, Ahi, Alo);
      bf16x8 Xhi[2], Xlo[2];
      if (!din1) {
        const unsigned int* rx = ring + ((g - 1) * 2 + (t & 1)) * 16 * 68;
        load_Apk(rx, c16, q16, Xhi, Xlo);
      }
      unsigned int* wb = ring + (g * 2 + (t & 1)) * 16 * 68;

#pragma unroll
      for (int ht = 0; ht < 2; ++ht) {
        f32x4 aR  = {b_r[ht],  b_r[ht],  b_r[ht],  b_r[ht]};
        f32x4 aZ  = {b_z[ht],  b_z[ht],  b_z[ht],  b_z[ht]};
        f32x4 aHN = {b_hn[ht], b_hn[ht], b_hn[ht], b_hn[ht]};
        f32x4 aIN = {b_in[ht], b_in[ht], b_in[ht], b_in[ht]};
        aR  = mm3(aR,  Ahi, Alo, Bh[ht][0]);
        aZ  = mm3(aZ,  Ahi, Alo, Bh[ht][1]);
        aHN = mm3(aHN, Ahi, Alo, Bh[ht][2]);
        if (din1) {
#pragma unroll
          for (int q = 0; q < 4; ++q) {
            aR[q]  += xcur[q] * w_r[ht];
            aZ[q]  += xcur[q] * w_z[ht];
            aIN[q] += xcur[q] * w_n[ht];
          }
        } else {
          aR  = mm2(aR,  Xhi, Xlo, Bx[ht][0]);
          aZ  = mm2(aZ,  Xhi, Xlo, Bx[ht][1]);
          aIN = mm2(aIN, Xhi, Xlo, Bx[ht][2]);
        }
#pragma unroll
        for (int q = 0; q < 4; ++q) {
          float r = __builtin_amdgcn_rcpf(1.f + __expf(-aR[q]));
          float z = __builtin_amdgcn_rcpf(1.f + __expf(-aZ[q]));
          float na = aIN[q] + r * aHN[q];
          na = fminf(fmaxf(na, -15.f), 15.f);
          float e2 = __expf(2.f * na);
          float n = (e2 - 1.f) * __builtin_amdgcn_rcpf(e2 + 1.f);
          float h = n + z * (hreg[ht][q] - n);
          hreg[ht][q] = h;
          wb[(4 * q16 + q) * 68 + cH[ht]] = pack_hl(h);
        }
        if (!IS_DEC && t == 511) {
#pragma unroll
          for (int q = 0; q < 4; ++q)
            P.hfin_wr[((size_t)g * 2048 + row_base + 4 * q16 + q) * 64 + cH[ht]] =
                hreg[ht][q];
        }
      }

      if (din1 && t + 1 < 512) {           // prefetch next step's x
        const float* xp = P.xseq + (size_t)row_base * 512 + (t + 1);
#pragma unroll
        for (int q = 0; q < 4; ++q) xcur[q] = xp[(size_t)(4 * q16 + q) * 512];
      }
    }
    wg_barrier();
  }
}

// ---------------------------------------------------------------------------
extern "C" void kernel_launch(void* const* d_in, const int* in_sizes, int n_in,
                              void* d_out, int out_size, void* d_ws, size_t ws_size,
                              hipStream_t stream) {
  (void)in_sizes; (void)n_in; (void)out_size; (void)ws_size;
  const float* inputs  = (const float*)d_in[0];
  const float* outputs = (const float*)d_in[1];

  unsigned short* frags = (unsigned short*)d_ws;                // 593920 B
  float* hfin = (float*)((char*)d_ws + 602112);                 // 1.5 MB

  static const int ofs[6]  = {2, 6, 10, 14, 18, 22};  // enc0,enc1,enc2,c1,c2,c3
  static const int dins[6] = {1, 60, 60, 1, 60, 60};

  PrepArgs pa;
  for (int ci = 0; ci < 6; ++ci) {
    pa.w[ci * 2 + 0]   = (const float*)d_in[ofs[ci] + 0];  // wih
    pa.w[ci * 2 + 1]   = (const float*)d_in[ofs[ci] + 1];  // whh
    pa.din[ci * 2 + 0] = dins[ci];
    pa.din[ci * 2 + 1] = 60;
  }
  pa.w[12] = (const float*)d_in[26];                       // lin_w
  pa.din[12] = 60;
  pa.out = frags;
  prep_frags<<<dim3(1160), dim3(256), 0, stream>>>(pa);

  PhaseArgs ea;
  ea.xseq = inputs; ea.frags = frags;
  for (int gg = 0; gg < 3; ++gg) {
    ea.cell[gg].bih     = (const float*)d_in[ofs[gg] + 2];
    ea.cell[gg].bhh     = (const float*)d_in[ofs[gg] + 3];
    ea.cell[gg].wih_vec = (const float*)d_in[ofs[gg] + 0];
  }
  ea.hfin_rd = hfin; ea.hfin_wr = hfin;
  ea.lin_b = (const float*)d_in[27];
  ea.y = (float*)d_out;
  gru_phase<0><<<dim3(128), dim3(384), 0, stream>>>(ea);

  PhaseArgs da = ea;
  da.xseq = outputs;
  for (int gg = 0; gg < 3; ++gg) {
    da.cell[gg].bih     = (const float*)d_in[ofs[3 + gg] + 2];
    da.cell[gg].bhh     = (const float*)d_in[ofs[3 + gg] + 3];
    da.cell[gg].wih_vec = (const float*)d_in[ofs[3 + gg] + 0];
  }
  gru_phase<1><<<dim3(128), dim3(384), 0, stream>>>(da);
}

// Round 5
// 1638.238 us; speedup vs baseline: 10.0086x; 1.6266x over previous
//
#include <hip/hip_runtime.h>
#include <hip/hip_bf16.h>

// ============================================================================
// GRU seq2seq (3-layer enc + 3-cell dec + linear), B=2048, H=60, F=1, fp32.
//
// Round 5 = round 2 structure (best: 865us/phase) + full-chip occupancy:
//  - 256 blocks x 8 batch-rows (was 128 x 16): every CU hosts one block.
//    MFMA rows 8-15 are padding (init 0, bounded dynamics, never stored).
//  - 12 waves/block, 4 waves/group, hi/lo bf16 ring planes (stride 72),
//    VGPR/AGPR-resident weights, __launch_bounds__(768, 3) (VGPR ~80, no spill).
//  - Split MFMA accumulator chains (3+3), both A-loads issued up front,
//    lgkmcnt-only barrier (no vmcnt drain each step).
// ============================================================================

typedef float  f32x4  __attribute__((ext_vector_type(4)));
typedef short  bf16x8 __attribute__((ext_vector_type(8)));

#define ROWS 8
#define NBLK (2048 / ROWS)

struct CellB  { const float* bih; const float* bhh; const float* wih_vec; };
struct PhaseArgs {
  const float* xseq;          // [2048][512] fp32
  const unsigned short* frags;
  CellB cell[3];
  const float* hfin_rd;       // dec: [3][2048][64] fp32
  float* hfin_wr;             // enc
  const float* lin_w;         // [60]
  const float* lin_b;         // [1]
  float* y;                   // [2048][512]
};
struct PrepArgs {
  const float* w[12];         // cell-major: (wih, whh) x 6 cells
  int din[12];
  unsigned short* out;
};

__device__ __forceinline__ unsigned int rne16(float x) {
  unsigned int u = __float_as_uint(x);
  return (u + 0x7fffu + ((u >> 16) & 1u)) >> 16;   // round-to-nearest-even bf16
}
__device__ __forceinline__ float bf2f(unsigned int b) {
  return __uint_as_float(b << 16);
}
union BU { __hip_bfloat16 b; unsigned short u; };
__device__ __forceinline__ unsigned short f2bf(float x) {
  BU c; c.b = __float2bfloat16(x); return c.u;
}
__device__ __forceinline__ float bfu2f(unsigned short s) {
  BU c; c.u = s; return __bfloat162float(c.b);
}
__device__ __forceinline__ void wg_barrier() {
  asm volatile("s_waitcnt lgkmcnt(0)" ::: "memory");
  __builtin_amdgcn_s_barrier();
}

// ---------------------------------------------------------------------------
// Prep: build B-fragments (bf16 hi/lo) for all 6 cells x {wih, whh}.
// frag layout: frag_idx = ((cell*2+mat)*12 + tile)*4 + s2*2 + sp
//              short off = frag_idx*512 + lane*8 + e
// ---------------------------------------------------------------------------
__global__ void prep_frags(PrepArgs P) {
  int id = blockIdx.x * 256 + threadIdx.x;       // 1152*256 = 294912 total
  int e    = id & 7;
  int lane = (id >> 3) & 63;
  int sp   = (id >> 9) & 1;
  int s2   = (id >> 10) & 1;
  int rest = id >> 11;
  int tile = rest % 12;
  int cm   = rest / 12;
  if (cm >= 12) return;
  const float* W = P.w[cm];
  int din = P.din[cm];
  int c = tile * 16 + (lane & 15);
  int j = c & 63, sec = c >> 6;                  // sec: 0=r,1=z,2=n
  int k = s2 * 32 + (lane >> 4) * 8 + e;
  float v = 0.f;
  if (j < 60 && k < din) v = W[(sec * 60 + j) * din + k];
  unsigned int hi = rne16(v);
  unsigned short o = (unsigned short)(sp ? rne16(v - bf2f(hi)) : hi);
  P.out[id] = o;
}

// ---------------------------------------------------------------------------
// A-fragment loads from hi/lo bf16 planes (row stride 72 shorts = 144 B).
// ---------------------------------------------------------------------------
__device__ __forceinline__ void load_A(const unsigned short* baseH,
                                       const unsigned short* baseL,
                                       int c16, int q16,
                                       bf16x8 Ahi[2], bf16x8 Alo[2]) {
  const unsigned short* pH = baseH + c16 * 72 + q16 * 8;
  const unsigned short* pL = baseL + c16 * 72 + q16 * 8;
  Ahi[0] = *(const bf16x8*)(pH);
  Ahi[1] = *(const bf16x8*)(pH + 32);
  Alo[0] = *(const bf16x8*)(pL);
  Alo[1] = *(const bf16x8*)(pL + 32);
}

// 3-product (hi*Whi + lo*Whi + hi*Wlo), two independent 3-deep chains
__device__ __forceinline__ f32x4 mm3(f32x4 acc, const bf16x8 Ahi[2],
                                     const bf16x8 Alo[2], const bf16x8 B[2][2]) {
  f32x4 a2 = {0.f, 0.f, 0.f, 0.f};
  acc = __builtin_amdgcn_mfma_f32_16x16x32_bf16(Ahi[0], B[0][0], acc, 0, 0, 0);
  a2  = __builtin_amdgcn_mfma_f32_16x16x32_bf16(Alo[0], B[0][0], a2,  0, 0, 0);
  acc = __builtin_amdgcn_mfma_f32_16x16x32_bf16(Ahi[1], B[1][0], acc, 0, 0, 0);
  a2  = __builtin_amdgcn_mfma_f32_16x16x32_bf16(Alo[1], B[1][0], a2,  0, 0, 0);
  acc = __builtin_amdgcn_mfma_f32_16x16x32_bf16(Ahi[0], B[0][1], acc, 0, 0, 0);
  a2  = __builtin_amdgcn_mfma_f32_16x16x32_bf16(Ahi[1], B[1][1], a2,  0, 0, 0);
  return acc + a2;
}
// 2-product (hi*Whi + lo*Whi), two independent 2-deep chains
__device__ __forceinline__ f32x4 mm2(f32x4 acc, const bf16x8 Ahi[2],
                                     const bf16x8 Alo[2], const bf16x8 B[2]) {
  f32x4 a2 = {0.f, 0.f, 0.f, 0.f};
  acc = __builtin_amdgcn_mfma_f32_16x16x32_bf16(Ahi[0], B[0], acc, 0, 0, 0);
  a2  = __builtin_amdgcn_mfma_f32_16x16x32_bf16(Alo[0], B[0], a2,  0, 0, 0);
  acc = __builtin_amdgcn_mfma_f32_16x16x32_bf16(Ahi[1], B[1], acc, 0, 0, 0);
  a2  = __builtin_amdgcn_mfma_f32_16x16x32_bf16(Alo[1], B[1], a2,  0, 0, 0);
  return acc + a2;
}

// ---------------------------------------------------------------------------
// Fused 3-stage GRU pipeline. IS_DEC=0: encoder; IS_DEC=1: decoder (+linear).
// ---------------------------------------------------------------------------
template <int IS_DEC>
__global__ __launch_bounds__(768, 3) void gru_phase(PhaseArgs P) {
  __shared__ alignas(16) unsigned short ringH[3 * 2 * 16 * 72];
  __shared__ alignas(16) unsigned short ringL[3 * 2 * 16 * 72];
  __shared__ float y_part[2][4][16];

  const int tid  = threadIdx.x;
  const int lane = tid & 63;
  const int wid  = tid >> 6;
  const int g    = wid >> 2;      // layer/cell index 0..2
  const int w    = wid & 3;       // tile-triple index 0..3
  const int c16  = lane & 15;
  const int q16  = lane >> 4;
  const int row_base = blockIdx.x * ROWS;
  const int c    = w * 16 + c16;  // logical h-column 0..63
  const bool cv  = (c < 60);
  const int cell = (IS_DEC ? 3 : 0) + g;
  const bool din1 = (g == 0);
  const bool rv   = (q16 < 2);    // rows 4*q16+q valid only for q16<2 (ROWS=8)

  // per-lane constants
  const float* bih = P.cell[g].bih;
  const float* bhh = P.cell[g].bhh;
  float b_r  = cv ? bih[c] + bhh[c]           : 0.f;
  float b_z  = cv ? bih[60 + c] + bhh[60 + c] : 0.f;
  float b_hn = cv ? bhh[120 + c]              : 0.f;
  float b_in = cv ? bih[120 + c]              : 0.f;
  float w_r = 0.f, w_z = 0.f, w_n = 0.f;
  if (din1 && cv) {
    const float* wv = P.cell[g].wih_vec;
    w_r = wv[c]; w_z = wv[60 + c]; w_n = wv[120 + c];
  }
  float lw = 0.f, lb = 0.f;
  if (IS_DEC && g == 2) { lw = cv ? P.lin_w[c] : 0.f; lb = P.lin_b[0]; }

  // persistent weight fragments
  bf16x8 Bh[3][2][2], Bx[3][2];
#pragma unroll
  for (int T = 0; T < 3; ++T)
#pragma unroll
    for (int s2 = 0; s2 < 2; ++s2) {
      const int tile = w + 4 * T;
#pragma unroll
      for (int sp = 0; sp < 2; ++sp)
        Bh[T][s2][sp] = *(const bf16x8*)(P.frags +
            (size_t)(((cell * 2 + 1) * 12 + tile) * 4 + s2 * 2 + sp) * 512 + lane * 8);
      Bx[T][s2] = *(const bf16x8*)(P.frags +
          (size_t)(((cell * 2 + 0) * 12 + tile) * 4 + s2 * 2 + 0) * 512 + lane * 8);
    }

  // h0 (enc: zeros; dec: encoder final h for valid rows) + ring init
  float hreg[4];
#pragma unroll
  for (int q = 0; q < 4; ++q) {
    float h0 = 0.f;
    if (IS_DEC && rv)
      h0 = P.hfin_rd[((size_t)(2 - g) * 2048 + row_base + 4 * q16 + q) * 64 + c];
    hreg[q] = h0;
    unsigned short hb = f2bf(h0);
    unsigned short lo = f2bf(h0 - bfu2f(hb));
    int ro = ((g * 2 + 1) * 16 + 4 * q16 + q) * 72 + c;
    ringH[ro] = hb; ringL[ro] = lo;
  }

  // x prefetch (t=0) for din=1 waves (valid rows only; padding rows x=0)
  float xcur[4] = {0.f, 0.f, 0.f, 0.f};
  if (din1 && rv) {
    const float* xp = P.xseq + (size_t)row_base * 512;
#pragma unroll
    for (int q = 0; q < 4; ++q) xcur[q] = xp[(size_t)(4 * q16 + q) * 512];
  }
  wg_barrier();

  const int NS = IS_DEC ? 515 : 514;
#pragma unroll 1
  for (int s = 0; s < NS; ++s) {
    // decoder: finalize y for t = s-3 (partials written last slot)
    if (IS_DEC && g == 2 && w == 0 && lane < ROWS) {
      int ty = s - 3;
      if (ty >= 0) {
        float yv = y_part[ty & 1][0][lane] + y_part[ty & 1][1][lane] +
                   y_part[ty & 1][2][lane] + y_part[ty & 1][3][lane] + lb;
        P.y[(size_t)(row_base + lane) * 512 + ty] = yv;
      }
    }

    const int t = s - g;
    if (t >= 0 && t < 512) {
      // ---- issue both A-fragment loads up front
      const int rdo = (g * 2 + ((t + 1) & 1)) * 16 * 72;
      bf16x8 Ahi[2], Alo[2];
      load_A(ringH + rdo, ringL + rdo, c16, q16, Ahi, Alo);
      bf16x8 Xhi[2], Xlo[2];
      if (!din1) {
        const int rxo = ((g - 1) * 2 + (t & 1)) * 16 * 72;
        load_A(ringH + rxo, ringL + rxo, c16, q16, Xhi, Xlo);
      }

      f32x4 aR  = {b_r, b_r, b_r, b_r};
      f32x4 aZ  = {b_z, b_z, b_z, b_z};
      f32x4 aHN = {b_hn, b_hn, b_hn, b_hn};
      f32x4 aIN = {b_in, b_in, b_in, b_in};
      aR  = mm3(aR,  Ahi, Alo, Bh[0]);
      aZ  = mm3(aZ,  Ahi, Alo, Bh[1]);
      aHN = mm3(aHN, Ahi, Alo, Bh[2]);

      if (din1) {
#pragma unroll
        for (int q = 0; q < 4; ++q) {
          aR[q]  += xcur[q] * w_r;
          aZ[q]  += xcur[q] * w_z;
          aIN[q] += xcur[q] * w_n;
        }
        if (rv && t + 1 < 512) {                // prefetch next step's x
          const float* xp = P.xseq + (size_t)row_base * 512 + (t + 1);
#pragma unroll
          for (int q = 0; q < 4; ++q) xcur[q] = xp[(size_t)(4 * q16 + q) * 512];
        }
      } else {
        aR  = mm2(aR,  Xhi, Xlo, Bx[0]);
        aZ  = mm2(aZ,  Xhi, Xlo, Bx[1]);
        aIN = mm2(aIN, Xhi, Xlo, Bx[2]);
      }

      // ---- activations + state update (full fp32)
#pragma unroll
      for (int q = 0; q < 4; ++q) {
        float r = __builtin_amdgcn_rcpf(1.f + __expf(-aR[q]));
        float z = __builtin_amdgcn_rcpf(1.f + __expf(-aZ[q]));
        float na = aIN[q] + r * aHN[q];
        na = fminf(fmaxf(na, -15.f), 15.f);
        float e2 = __expf(2.f * na);
        float n = (e2 - 1.f) * __builtin_amdgcn_rcpf(e2 + 1.f);
        hreg[q] = n + z * (hreg[q] - n);
      }

      // ---- publish h_t (hi/lo planes) to ring[parity t&1]
      {
        unsigned short* wH = ringH + (g * 2 + (t & 1)) * 16 * 72;
        unsigned short* wL = ringL + (g * 2 + (t & 1)) * 16 * 72;
#pragma unroll
        for (int q = 0; q < 4; ++q) {
          float h = hreg[q];
          unsigned short hb = f2bf(h);
          unsigned short lo = f2bf(h - bfu2f(hb));
          int ro = (4 * q16 + q) * 72 + c;
          wH[ro] = hb; wL[ro] = lo;
        }
      }

      // ---- encoder: store final hidden state (valid rows only)
      if (!IS_DEC && t == 511 && rv) {
#pragma unroll
        for (int q = 0; q < 4; ++q)
          P.hfin_wr[((size_t)g * 2048 + row_base + 4 * q16 + q) * 64 + c] = hreg[q];
      }

      // ---- decoder: y partials (reduce over this wave's 16 columns)
      if (IS_DEC && g == 2) {
        float part[4];
#pragma unroll
        for (int q = 0; q < 4; ++q) part[q] = hreg[q] * lw;
#pragma unroll
        for (int m = 1; m < 16; m <<= 1) {
#pragma unroll
          for (int q = 0; q < 4; ++q) part[q] += __shfl_xor(part[q], m, 64);
        }
        if (c16 == 0) {
#pragma unroll
          for (int q = 0; q < 4; ++q) y_part[t & 1][w][4 * q16 + q] = part[q];
        }
      }
    }
    wg_barrier();
  }
}

// ---------------------------------------------------------------------------
extern "C" void kernel_launch(void* const* d_in, const int* in_sizes, int n_in,
                              void* d_out, int out_size, void* d_ws, size_t ws_size,
                              hipStream_t stream) {
  (void)in_sizes; (void)n_in; (void)out_size; (void)ws_size;
  const float* inputs  = (const float*)d_in[0];
  const float* outputs = (const float*)d_in[1];

  unsigned short* frags = (unsigned short*)d_ws;                 // 589824 B
  float* hfin = (float*)((char*)d_ws + (size_t)6 * 2 * 12 * 4 * 512 * 2); // 1.5 MB

  static const int ofs[6]  = {2, 6, 10, 14, 18, 22};  // enc0,enc1,enc2,c1,c2,c3
  static const int dins[6] = {1, 60, 60, 1, 60, 60};

  PrepArgs pa;
  for (int ci = 0; ci < 6; ++ci) {
    pa.w[ci * 2 + 0]   = (const float*)d_in[ofs[ci] + 0];  // wih
    pa.w[ci * 2 + 1]   = (const float*)d_in[ofs[ci] + 1];  // whh
    pa.din[ci * 2 + 0] = dins[ci];
    pa.din[ci * 2 + 1] = 60;
  }
  pa.out = frags;
  prep_frags<<<dim3(1152), dim3(256), 0, stream>>>(pa);

  PhaseArgs ea;
  ea.xseq = inputs; ea.frags = frags;
  for (int gg = 0; gg < 3; ++gg) {
    ea.cell[gg].bih     = (const float*)d_in[ofs[gg] + 2];
    ea.cell[gg].bhh     = (const float*)d_in[ofs[gg] + 3];
    ea.cell[gg].wih_vec = (const float*)d_in[ofs[gg] + 0];
  }
  ea.hfin_rd = hfin; ea.hfin_wr = hfin;
  ea.lin_w = (const float*)d_in[26]; ea.lin_b = (const float*)d_in[27];
  ea.y = (float*)d_out;
  gru_phase<0><<<dim3(NBLK), dim3(768), 0, stream>>>(ea);

  PhaseArgs da = ea;
  da.xseq = outputs;
  for (int gg = 0; gg < 3; ++gg) {
    da.cell[gg].bih     = (const float*)d_in[ofs[3 + gg] + 2];
    da.cell[gg].bhh     = (const float*)d_in[ofs[3 + gg] + 3];
    da.cell[gg].wih_vec = (const float*)d_in[ofs[3 + gg] + 0];
  }
  gru_phase<1><<<dim3(NBLK), dim3(768), 0, stream>>>(da);
}